// Round 11
// baseline (33.334 us; speedup 1.0000x reference)
//
#include <hip/hip_runtime.h>
#include <hip/hip_fp16.h>

// ============================================================================
// PC-DONN collapse (validated rounds 1-10, absmax 0.0):
//   |H|==1 and |exp(i*phase)|==1; FFT pairs obey Parseval => sum|field|^2 is
//   exactly invariant through the whole propagation chain. Hence
//       out[b] = (1/M) * sum_p x_in[b,p]^2 * sum_m |T_m[p]|^2
//   with T_m = fftshift(IDFT2_unnorm(C_m * G)), G = sqrt(p_v + 1e-12).
//
// Round 11: R10 = 24.2us; floor ~5us. K2's remaining cost is its LDS/barrier
// machinery (stage->FFT(3 barriers)->|T|^2->re-read), not arithmetic.
// Column FFTs are independent and FFT-128 fits in ONE wave's registers:
// 64 lanes x 2 cplx, radix-2 DIF via __shfl_xor; stage 1 in-lane (l, l+64),
// then spans 32,16,8,4,2,1 (one shfl_xor pair per slot); twiddles
// precomputed per lane (5 sincosf, reused for all m). DIF's bit-reversed
// output order is folded into the final W row index (free permutation).
// K2' = zero LDS, zero barriers; m-loop iterations independent (deep ILP);
// mid column loads are 512B contiguous. 2 atomicAdds/lane at the end
// (scattered lines, no same-line hotspot).
// ============================================================================

struct cplx { float x, y; };
__device__ __forceinline__ cplx cadd(cplx a, cplx b){ return {a.x+b.x, a.y+b.y}; }
__device__ __forceinline__ cplx csub(cplx a, cplx b){ return {a.x-b.x, a.y-b.y}; }
__device__ __forceinline__ cplx cmul(cplx a, cplx b){ return {a.x*b.x - a.y*b.y, a.x*b.y + a.y*b.x}; }
__device__ __forceinline__ cplx cmuli(cplx a){ return {-a.y, a.x}; }   // * (+i): inverse-FFT sign

__device__ __forceinline__ void idft4(cplx&A,cplx&B,cplx&C,cplx&D){
    cplx e0=cadd(A,C), e1=csub(A,C), o0=cadd(B,D), o1=csub(B,D);
    cplx i1 = cmuli(o1);
    A=cadd(e0,o0); B=cadd(e1,i1); C=csub(e0,o0); D=csub(e1,i1);
}
__device__ __forceinline__ void idft8(cplx a[8]){
    cplx e0=a[0],e1=a[2],e2=a[4],e3=a[6];
    cplx o0=a[1],o1=a[3],o2=a[5],o3=a[7];
    idft4(e0,e1,e2,e3); idft4(o0,o1,o2,o3);
    const float Ch = 0.70710678118654752f;
    cplx t1 = cmul(o1, cplx{ Ch, Ch});
    cplx t2 = cmuli(o2);
    cplx t3 = cmul(o3, cplx{-Ch, Ch});
    a[0]=cadd(e0,o0); a[4]=csub(e0,o0);
    a[1]=cadd(e1,t1); a[5]=csub(e1,t1);
    a[2]=cadd(e2,t2); a[6]=csub(e2,t2);
    a[3]=cadd(e3,t3); a[7]=csub(e3,t3);
}
__device__ __forceinline__ void idft16(cplx a[16]){
    cplx e[8]={a[0],a[2],a[4],a[6],a[8],a[10],a[12],a[14]};
    cplx o[8]={a[1],a[3],a[5],a[7],a[9],a[11],a[13],a[15]};
    idft8(e); idft8(o);
    const float Ch=0.70710678118654752f, c1=0.92387953251128674f, s1=0.38268343236508977f;
    const cplx w[8]={{1.f,0.f},{c1,s1},{Ch,Ch},{s1,c1},{0.f,1.f},{-s1,c1},{-Ch,Ch},{-c1,s1}};
    #pragma unroll
    for(int n=0;n<8;++n){ cplx t=cmul(o[n],w[n]); a[n]=cadd(e[n],t); a[n+8]=csub(e[n],t); }
}

#define LDSP 130   // padded row stride (cplx)
#define NR   16    // rows per K1 tile
#define CH   10    // screens per K2 wave-task

// In-place FFT-128 of (blockDim.x/8) rows in fld. r=tid>>3 row, t=tid&7.
__device__ __forceinline__ void fft128_rows(cplx* fld, const cplx* tw, int tid)
{
    const int r = tid >> 3, t = tid & 7;
    cplx* row = fld + r * LDSP;
    {   cplx a[16];
        #pragma unroll
        for (int k1 = 0; k1 < 16; ++k1) a[k1] = row[t + 8*k1];
        idft16(a);
        #pragma unroll
        for (int n1 = 0; n1 < 16; ++n1) row[t + 8*n1] = cmul(a[n1], tw[(n1*t) & 127]);
    }
    __syncthreads();
    {   cplx b0[8], b1[8];
        #pragma unroll
        for (int k2 = 0; k2 < 8; ++k2) { b0[k2] = row[8*t + k2]; b1[k2] = row[8*(t+8) + k2]; }
        idft8(b0); idft8(b1);
        __syncthreads();
        #pragma unroll
        for (int n2 = 0; n2 < 8; ++n2) {
            row[ t      + 16*n2] = b0[n2];
            row[(t + 8) + 16*n2] = b1[n2];
        }
    }
    __syncthreads();
}

__device__ __forceinline__ unsigned h2_to_u(__half2 h){
    union { __half2 h; unsigned u; } v; v.h = h; return v.u;
}

// K1: row FFTs of C*G -> transposed fp16 mid[m][c*128 + i]; m==0 blocks
// also zero Wsh (replay-safe accumulation base).
__global__ __launch_bounds__(128)
void rowfft_kernel(const float* __restrict__ c_noise, __half2* __restrict__ mid,
                   float* __restrict__ Wsh)
{
    __shared__ cplx fld[NR * LDSP];
    __shared__ cplx tw[128];
    const int m   = blockIdx.x;
    const int rb  = blockIdx.y * NR;
    const int tid = threadIdx.x;

    if (m == 0) {                       // zero Wsh: 8 blocks x 2048 floats
        float4* wz = (float4*)Wsh;
        #pragma unroll
        for (int k = 0; k < 4; ++k)
            wz[blockIdx.y*512 + k*128 + tid] = {0.f, 0.f, 0.f, 0.f};
    }

    {   float s, c;
        sincosf((float)tid * (float)(2.0 * M_PI / 128.0), &s, &c);
        tw[tid] = { c, s };
    }

    const float DF = 976.5625f;                  // 1/(N*DX)
    const float Ac = 2.5132741228718345e-7f;     // 2*pi*L^2
    const float Bc = 7.8956835208714865e-7f;     // 2*pi^2*L^2
    #pragma unroll
    for (int it = 0; it < NR; ++it) {
        const int i = rb + it, j = tid;
        float fi = (float)(((i+64)&127) - 64) * DF;
        float fj = (float)(((j+64)&127) - 64) * DF;
        float G  = sqrtf(Ac * expf(-Bc * (fi*fi + fj*fj)) + 1e-12f);
        float2 cv = ((const float2*)c_noise)[(size_t)m*16384 + i*128 + j];
        fld[it*LDSP + j] = { cv.x * G, cv.y * G };
    }
    __syncthreads();

    fft128_rows(fld, tw, tid);

    // transposed fp16 store: thread = column c; 16 rows = 64 B = 4 x uint4
    const int c = tid;
    uint4* dst4 = (uint4*)(mid + (size_t)m*16384 + (size_t)c*128 + rb);
    #pragma unroll
    for (int q = 0; q < 4; ++q) {
        uint4 pk;
        cplx v0 = fld[(4*q+0)*LDSP + c];
        cplx v1 = fld[(4*q+1)*LDSP + c];
        cplx v2 = fld[(4*q+2)*LDSP + c];
        cplx v3 = fld[(4*q+3)*LDSP + c];
        pk.x = h2_to_u(__floats2half2_rn(v0.x, v0.y));
        pk.y = h2_to_u(__floats2half2_rn(v1.x, v1.y));
        pk.z = h2_to_u(__floats2half2_rn(v2.x, v2.y));
        pk.w = h2_to_u(__floats2half2_rn(v3.x, v3.y));
        dst4[q] = pk;
    }
}

// K2': in-register wave FFT-128 per column. Wave = one column c; loops CH
// screens; lane l holds x[l] (slot0) and x[l+64] (slot1). Radix-2 DIF:
// stage span 64 in-lane with tw=e^{+2pi i l/128}; spans 32..1 via
// __shfl_xor with per-lane twiddle tw_s = (l&s)? e^{+2pi i (l&(s-1))/(2s)}
// : 1. Output at (slot v, lane l) = X[(bitrev6(l)<<1) | v]. Accumulate
// |X|^2 over m; 2 atomicAdds per lane into shifted Wsh at the end.
__global__ __launch_bounds__(256)
void colfft_acc_kernel(const __half2* __restrict__ mid,
                       float* __restrict__ Wsh, int M)
{
    const int tid = threadIdx.x;
    const int w   = tid >> 6, l = tid & 63;
    const int c   = blockIdx.x * 4 + w;          // column 0..127
    const int m0  = blockIdx.y * CH;
    const int m1  = (m0 + CH < M) ? (m0 + CH) : M;

    // per-lane twiddles (reused across all m)
    const float PI2 = 6.2831853071795865f;
    float s1, c1; sincosf(PI2 * (float)l * (1.0f/128.0f), &s1, &c1);
    float twr[6], twi[6];
    const int spans[6] = {32, 16, 8, 4, 2, 1};
    #pragma unroll
    for (int k = 0; k < 6; ++k) {
        const int s = spans[k];
        if (l & s) {
            float si, co;
            sincosf(PI2 * (float)(l & (s-1)) / (float)(2*s), &si, &co);
            twr[k] = co; twi[k] = si;
        } else { twr[k] = 1.f; twi[k] = 0.f; }
    }

    float acc0 = 0.f, acc1 = 0.f;
    #pragma unroll 2
    for (int m = m0; m < m1; ++m) {
        const __half2* col = mid + (size_t)m*16384 + (size_t)c*128;
        float2 a = __half22float2(col[l]);        // x[l]
        float2 b = __half22float2(col[l + 64]);   // x[l+64]

        // stage span 64 (in-lane): lo = a+b ; hi = (a-b)*e^{+2pi i l/128}
        float r0 = a.x + b.x,  i0 = a.y + b.y;
        float dr = a.x - b.x,  di = a.y - b.y;
        float r1 = dr*c1 - di*s1, i1 = dr*s1 + di*c1;

        // spans 32,16,8,4,2,1 via shfl_xor; both slots use same hi/tw
        #pragma unroll
        for (int k = 0; k < 6; ++k) {
            const int s = spans[k];
            const bool hi = (l & s) != 0;
            float pr, pi, d_r, d_i;
            pr = __shfl_xor(r0, s); pi = __shfl_xor(i0, s);
            d_r = hi ? (pr - r0) : (r0 + pr);
            d_i = hi ? (pi - i0) : (i0 + pi);
            r0 = d_r*twr[k] - d_i*twi[k]; i0 = d_r*twi[k] + d_i*twr[k];
            pr = __shfl_xor(r1, s); pi = __shfl_xor(i1, s);
            d_r = hi ? (pr - r1) : (r1 + pr);
            d_i = hi ? (pi - i1) : (i1 + pi);
            r1 = d_r*twr[k] - d_i*twi[k]; i1 = d_r*twi[k] + d_i*twr[k];
        }
        acc0 += r0*r0 + i0*i0;
        acc1 += r1*r1 + i1*i1;
    }

    // output rows: X[(bitrev6(l)<<1) | v]; fold fftshift (^64 on row & col)
    const int rb   = ((l&1)<<5)|((l&2)<<3)|((l&4)<<1)|((l&8)>>1)|((l&16)>>3)|((l&32)>>5);
    const int row0 = rb << 1, row1 = row0 | 1;
    const int cs   = c ^ 64;
    atomicAdd(&Wsh[((row0 ^ 64) << 7) + cs], acc0);
    atomicAdd(&Wsh[((row1 ^ 64) << 7) + cs], acc1);
}

// K3: out[b] = (1/M) * sum_p x[b,p]^2 * Wsh[p]. Linear float4 streams;
// x[b] (64KB) + Wsh (64KB, shared) are L2-hot.
__global__ __launch_bounds__(256)
void dot_kernel(const float* __restrict__ x, const float* __restrict__ Wsh,
                float* __restrict__ out, int M)
{
    const int b = blockIdx.x;
    const float4* x4 = (const float4*)(x + (size_t)b * 16384);
    const float4* w4 = (const float4*)Wsh;
    float acc = 0.f;
    #pragma unroll 4
    for (int k = threadIdx.x; k < 4096; k += 256) {
        float4 xv = x4[k], wv = w4[k];
        acc = fmaf(xv.x*xv.x, wv.x, acc);
        acc = fmaf(xv.y*xv.y, wv.y, acc);
        acc = fmaf(xv.z*xv.z, wv.z, acc);
        acc = fmaf(xv.w*xv.w, wv.w, acc);
    }
    #pragma unroll
    for (int off = 32; off > 0; off >>= 1) acc += __shfl_down(acc, off);
    __shared__ float part[4];
    if ((threadIdx.x & 63) == 0) part[threadIdx.x >> 6] = acc;
    __syncthreads();
    if (threadIdx.x == 0)
        out[b] = (part[0] + part[1] + part[2] + part[3]) / (float)M;
}

extern "C" void kernel_launch(void* const* d_in, const int* in_sizes, int n_in,
                              void* d_out, int out_size, void* d_ws, size_t ws_size,
                              hipStream_t stream)
{
    (void)n_in; (void)ws_size;
    const float* x_in    = (const float*)d_in[0];
    // d_in[1] (phases) provably does not affect the output (|exp(i*phase)|=1).
    const float* c_noise = (const float*)d_in[2];

    const int M = in_sizes[2] / (128*128*2);   // 100
    const int B = out_size;                    // 32

    __half2* mid = (__half2*)d_ws;                                   // 6.55 MB
    float*   Wsh = (float*)((char*)d_ws + (size_t)M*16384*sizeof(__half2)); // 64 KB

    const int chunks = (M + CH - 1) / CH;      // 10

    rowfft_kernel    <<<dim3(M, 8),       dim3(128), 0, stream>>>(c_noise, mid, Wsh);
    colfft_acc_kernel<<<dim3(32, chunks), dim3(256), 0, stream>>>(mid, Wsh, M);
    dot_kernel       <<<dim3(B),          dim3(256), 0, stream>>>(x_in, Wsh,
                                                                  (float*)d_out, M);
}

// Round 12
// 30.701 us; speedup vs baseline: 1.0857x; 1.0857x over previous
//
#include <hip/hip_runtime.h>
#include <hip/hip_fp16.h>

// ============================================================================
// PC-DONN collapse (validated rounds 1-11, absmax 0.0):
//   |H|==1 and |exp(i*phase)|==1; FFT pairs obey Parseval => sum|field|^2 is
//   exactly invariant through the whole propagation chain. Hence
//       out[b] = (1/M) * sum_p x_in[b,p]^2 * sum_m |T_m[p]|^2
//   with T_m = fftshift(IDFT2_unnorm(C_m * G)), G = sqrt(p_v + 1e-12).
//
// Round 12: R11 (wave-shfl FFT) regressed 24.2->33.3 (12 serial ds_permute
// ops x 10 serial screens at 1.25 blocks/CU = latency chain) -- falsifies
// "LDS machinery" as K2's cost. Revert K2 to R10's LDS form. The one R10
// phase never isolated: W atomic accumulation. Every pixel gets 50 device-
// scope atomicAdds (one per screen-pair block); 16 pixels/64B line -> ~800
// serialized RMWs per L2 line (~8us). Controlled experiment: K1/K3 byte-
// identical to R10; K2's atomics -> plain stores to Ppart[g][pixel]
// (3.3MB, zero atomics); new wred node: Wsh[p] = sum_g Ppart[g][p].
// Predict 24.2 -> ~17-19 if atomic theory right; ~24-26 if innocent.
// ============================================================================

struct cplx { float x, y; };
__device__ __forceinline__ cplx cadd(cplx a, cplx b){ return {a.x+b.x, a.y+b.y}; }
__device__ __forceinline__ cplx csub(cplx a, cplx b){ return {a.x-b.x, a.y-b.y}; }
__device__ __forceinline__ cplx cmul(cplx a, cplx b){ return {a.x*b.x - a.y*b.y, a.x*b.y + a.y*b.x}; }
__device__ __forceinline__ cplx cmuli(cplx a){ return {-a.y, a.x}; }   // * (+i): inverse-FFT sign

__device__ __forceinline__ void idft4(cplx&A,cplx&B,cplx&C,cplx&D){
    cplx e0=cadd(A,C), e1=csub(A,C), o0=cadd(B,D), o1=csub(B,D);
    cplx i1 = cmuli(o1);
    A=cadd(e0,o0); B=cadd(e1,i1); C=csub(e0,o0); D=csub(e1,i1);
}
__device__ __forceinline__ void idft8(cplx a[8]){
    cplx e0=a[0],e1=a[2],e2=a[4],e3=a[6];
    cplx o0=a[1],o1=a[3],o2=a[5],o3=a[7];
    idft4(e0,e1,e2,e3); idft4(o0,o1,o2,o3);
    const float Ch = 0.70710678118654752f;
    cplx t1 = cmul(o1, cplx{ Ch, Ch});
    cplx t2 = cmuli(o2);
    cplx t3 = cmul(o3, cplx{-Ch, Ch});
    a[0]=cadd(e0,o0); a[4]=csub(e0,o0);
    a[1]=cadd(e1,t1); a[5]=csub(e1,t1);
    a[2]=cadd(e2,t2); a[6]=csub(e2,t2);
    a[3]=cadd(e3,t3); a[7]=csub(e3,t3);
}
__device__ __forceinline__ void idft16(cplx a[16]){
    cplx e[8]={a[0],a[2],a[4],a[6],a[8],a[10],a[12],a[14]};
    cplx o[8]={a[1],a[3],a[5],a[7],a[9],a[11],a[13],a[15]};
    idft8(e); idft8(o);
    const float Ch=0.70710678118654752f, c1=0.92387953251128674f, s1=0.38268343236508977f;
    const cplx w[8]={{1.f,0.f},{c1,s1},{Ch,Ch},{s1,c1},{0.f,1.f},{-s1,c1},{-Ch,Ch},{-c1,s1}};
    #pragma unroll
    for(int n=0;n<8;++n){ cplx t=cmul(o[n],w[n]); a[n]=cadd(e[n],t); a[n+8]=csub(e[n],t); }
}

#define LDSP 130   // padded row stride (cplx)
#define NR   16    // rows (or cols) per tile
#define MG   2     // screens per K2 block (concurrent sub-groups; M%MG==0)

// In-place FFT-128 of (blockDim.x/8) rows in fld. r=tid>>3 row, t=tid&7.
__device__ __forceinline__ void fft128_rows(cplx* fld, const cplx* tw, int tid)
{
    const int r = tid >> 3, t = tid & 7;
    cplx* row = fld + r * LDSP;
    {   cplx a[16];
        #pragma unroll
        for (int k1 = 0; k1 < 16; ++k1) a[k1] = row[t + 8*k1];
        idft16(a);
        #pragma unroll
        for (int n1 = 0; n1 < 16; ++n1) row[t + 8*n1] = cmul(a[n1], tw[(n1*t) & 127]);
    }
    __syncthreads();
    {   cplx b0[8], b1[8];
        #pragma unroll
        for (int k2 = 0; k2 < 8; ++k2) { b0[k2] = row[8*t + k2]; b1[k2] = row[8*(t+8) + k2]; }
        idft8(b0); idft8(b1);
        __syncthreads();
        #pragma unroll
        for (int n2 = 0; n2 < 8; ++n2) {
            row[ t      + 16*n2] = b0[n2];
            row[(t + 8) + 16*n2] = b1[n2];
        }
    }
    __syncthreads();
}

__device__ __forceinline__ unsigned h2_to_u(__half2 h){
    union { __half2 h; unsigned u; } v; v.h = h; return v.u;
}

// K1: row FFTs of C*G -> transposed fp16 mid[m][c*128 + i]; m==0 blocks
// also zero Wsh (kept byte-identical to R10; wred overwrites Wsh anyway).
__global__ __launch_bounds__(128)
void rowfft_kernel(const float* __restrict__ c_noise, __half2* __restrict__ mid,
                   float* __restrict__ Wsh)
{
    __shared__ cplx fld[NR * LDSP];
    __shared__ cplx tw[128];
    const int m   = blockIdx.x;
    const int rb  = blockIdx.y * NR;
    const int tid = threadIdx.x;

    if (m == 0) {                       // zero Wsh: 8 blocks x 2048 floats
        float4* wz = (float4*)Wsh;
        #pragma unroll
        for (int k = 0; k < 4; ++k)
            wz[blockIdx.y*512 + k*128 + tid] = {0.f, 0.f, 0.f, 0.f};
    }

    {   float s, c;
        sincosf((float)tid * (float)(2.0 * M_PI / 128.0), &s, &c);
        tw[tid] = { c, s };
    }

    const float DF = 976.5625f;                  // 1/(N*DX)
    const float Ac = 2.5132741228718345e-7f;     // 2*pi*L^2
    const float Bc = 7.8956835208714865e-7f;     // 2*pi^2*L^2
    #pragma unroll
    for (int it = 0; it < NR; ++it) {
        const int i = rb + it, j = tid;
        float fi = (float)(((i+64)&127) - 64) * DF;
        float fj = (float)(((j+64)&127) - 64) * DF;
        float G  = sqrtf(Ac * expf(-Bc * (fi*fi + fj*fj)) + 1e-12f);
        float2 cv = ((const float2*)c_noise)[(size_t)m*16384 + i*128 + j];
        fld[it*LDSP + j] = { cv.x * G, cv.y * G };
    }
    __syncthreads();

    fft128_rows(fld, tw, tid);

    // transposed fp16 store: thread = column c; 16 rows = 64 B = 4 x uint4
    const int c = tid;
    uint4* dst4 = (uint4*)(mid + (size_t)m*16384 + (size_t)c*128 + rb);
    #pragma unroll
    for (int q = 0; q < 4; ++q) {
        uint4 pk;
        cplx v0 = fld[(4*q+0)*LDSP + c];
        cplx v1 = fld[(4*q+1)*LDSP + c];
        cplx v2 = fld[(4*q+2)*LDSP + c];
        cplx v3 = fld[(4*q+3)*LDSP + c];
        pk.x = h2_to_u(__floats2half2_rn(v0.x, v0.y));
        pk.y = h2_to_u(__floats2half2_rn(v1.x, v1.y));
        pk.z = h2_to_u(__floats2half2_rn(v2.x, v2.y));
        pk.w = h2_to_u(__floats2half2_rn(v3.x, v3.y));
        dst4[q] = pk;
    }
}

// K2: 2 screens concurrently (128-thread sub-groups); col FFT; |T|^2 in
// place; slab-sum; PLAIN stores to per-pair partials Ppart[g][pixel]
// (shift folded) -- zero atomics.
__global__ __launch_bounds__(256)
void colfft_part_kernel(const __half2* __restrict__ mid,
                        float* __restrict__ Ppart, int M)
{
    __shared__ cplx fld[MG * NR * LDSP];      // 2 slabs of 16 rows -> 33.3 KB
    __shared__ cplx tw[128];
    const int g   = blockIdx.x;               // screen pair
    const int cb  = blockIdx.y * NR;          // column tile base (16-aligned)
    const int tid = threadIdx.x;
    const int grp = tid >> 7;                 // screen sub-group 0..1
    const int lt  = tid & 127;                // lane within sub-group

    if (tid < 128) {
        float s, c;
        sincosf((float)tid * (float)(2.0 * M_PI / 128.0), &s, &c);
        tw[tid] = { c, s };
    }

    // load: sub-group grp loads screen m's 16-column tile (fp16 -> f32)
    {
        const int m = g*MG + grp;             // M % MG == 0
        #pragma unroll
        for (int it = 0; it < NR; ++it) {
            float2 v = __half22float2(mid[(size_t)m*16384 + (size_t)(cb + it)*128 + lt]);
            fld[(grp*NR + it)*LDSP + lt] = { v.x, v.y };
        }
    }
    __syncthreads();

    fft128_rows(fld, tw, tid);                // 32 rows across both slabs

    // |T|^2 in place (as .x): fld[it][lt] = |T2d[row lt][col cb+it]|^2
    #pragma unroll
    for (int it = 0; it < NR; ++it) {
        cplx v = fld[(grp*NR + it)*LDSP + lt];
        fld[(grp*NR + it)*LDSP + lt].x = v.x*v.x + v.y*v.y;
    }
    __syncthreads();

    // store per-pair partial at the SHIFTED pixel index (no atomics):
    // value (it, lt2) -> Ppart[g*16384 + (lt2^64)*128 + (cb^64) + it];
    // tid-consecutive -> 16 consecutive floats per 16-lane group.
    const int c0 = cb ^ 64;
    float* Pg = Ppart + (size_t)g * 16384;
    #pragma unroll
    for (int k = 0; k < 8; ++k) {
        int v   = k*256 + tid;                // 0..2047
        int lt2 = v >> 4, it = v & 15;
        float wv = fld[(       it)*LDSP + lt2].x
                 + fld[(NR  +  it)*LDSP + lt2].x;
        Pg[((lt2 ^ 64) << 7) + c0 + it] = wv;
    }
}

// wred: Wsh[p] = sum_{g<G} Ppart[g][p]; fully coalesced, fixed order.
__global__ __launch_bounds__(256)
void wred_kernel(const float* __restrict__ Ppart, float* __restrict__ Wsh, int G)
{
    const int p = blockIdx.x * 256 + threadIdx.x;
    float s = 0.f;
    #pragma unroll 5
    for (int g = 0; g < G; ++g) s += Ppart[(size_t)g*16384 + p];
    Wsh[p] = s;
}

// K3: out[b] = (1/M) * sum_p x[b,p]^2 * Wsh[p]. Linear float4 streams;
// x[b] (64KB) + Wsh (64KB, shared) are L2-hot.
__global__ __launch_bounds__(256)
void dot_kernel(const float* __restrict__ x, const float* __restrict__ Wsh,
                float* __restrict__ out, int M)
{
    const int b = blockIdx.x;
    const float4* x4 = (const float4*)(x + (size_t)b * 16384);
    const float4* w4 = (const float4*)Wsh;
    float acc = 0.f;
    #pragma unroll 4
    for (int k = threadIdx.x; k < 4096; k += 256) {
        float4 xv = x4[k], wv = w4[k];
        acc = fmaf(xv.x*xv.x, wv.x, acc);
        acc = fmaf(xv.y*xv.y, wv.y, acc);
        acc = fmaf(xv.z*xv.z, wv.z, acc);
        acc = fmaf(xv.w*xv.w, wv.w, acc);
    }
    #pragma unroll
    for (int off = 32; off > 0; off >>= 1) acc += __shfl_down(acc, off);
    __shared__ float part[4];
    if ((threadIdx.x & 63) == 0) part[threadIdx.x >> 6] = acc;
    __syncthreads();
    if (threadIdx.x == 0)
        out[b] = (part[0] + part[1] + part[2] + part[3]) / (float)M;
}

extern "C" void kernel_launch(void* const* d_in, const int* in_sizes, int n_in,
                              void* d_out, int out_size, void* d_ws, size_t ws_size,
                              hipStream_t stream)
{
    (void)n_in; (void)ws_size;
    const float* x_in    = (const float*)d_in[0];
    // d_in[1] (phases) provably does not affect the output (|exp(i*phase)|=1).
    const float* c_noise = (const float*)d_in[2];

    const int M = in_sizes[2] / (128*128*2);   // 100 (M % MG == 0)
    const int B = out_size;                    // 32

    const int G = M / MG;                      // 50 screen pairs

    __half2* mid   = (__half2*)d_ws;                                  // 6.55 MB
    float*   Ppart = (float*)((char*)d_ws + (size_t)M*16384*sizeof(__half2));
    float*   Wsh   = Ppart + (size_t)G*16384;                         // 64 KB

    rowfft_kernel    <<<dim3(M, 8), dim3(128), 0, stream>>>(c_noise, mid, Wsh);
    colfft_part_kernel<<<dim3(G, 8), dim3(256), 0, stream>>>(mid, Ppart, M);
    wred_kernel      <<<dim3(64),   dim3(256), 0, stream>>>(Ppart, Wsh, G);
    dot_kernel       <<<dim3(B),    dim3(256), 0, stream>>>(x_in, Wsh,
                                                            (float*)d_out, M);
}

// Round 13
// 25.298 us; speedup vs baseline: 1.3176x; 1.2136x over previous
//
#include <hip/hip_runtime.h>
#include <hip/hip_fp16.h>

// ============================================================================
// PC-DONN collapse (validated rounds 1-12, absmax 0.0):
//   |H|==1 and |exp(i*phase)|==1; FFT pairs obey Parseval => sum|field|^2 is
//   exactly invariant through the whole propagation chain. Hence
//       out[b] = (1/M) * sum_p x_in[b,p]^2 * sum_m |T_m[p]|^2
//   with T_m = fftshift(IDFT2_unnorm(C_m * G)), G = sqrt(p_v + 1e-12).
//
// Round 13: R12 acquitted the atomics (stores+wred = 30.7 > R10's 24.2).
// Calibrating overhead from rounds where K2 WAS visible (R3/R4/R7: fixed
// ~5us, K1 ~4.5us, K3 ~2.5us) => R10's K2 ~= 12-14us, 3x K1 at the SAME
// total wave count and LESS global traffic. Remaining structural delta:
// block shape (K2: 4-wave blocks, wide barriers, 33KiB LDS; K1: 2-wave
// blocks, 17KiB). Experiment: K2 rebuilt as a structural clone of K1 --
// MG=1, 128 threads, 800 blocks, same FFT body -- with |T|^2 + 16
// coalesced lane-atomicAdds per thread as epilogue (R12: atomic ~ store).
// K1/K3 byte-identical to R10. Predict 24.2 -> ~16-18 if theory right.
// ============================================================================

struct cplx { float x, y; };
__device__ __forceinline__ cplx cadd(cplx a, cplx b){ return {a.x+b.x, a.y+b.y}; }
__device__ __forceinline__ cplx csub(cplx a, cplx b){ return {a.x-b.x, a.y-b.y}; }
__device__ __forceinline__ cplx cmul(cplx a, cplx b){ return {a.x*b.x - a.y*b.y, a.x*b.y + a.y*b.x}; }
__device__ __forceinline__ cplx cmuli(cplx a){ return {-a.y, a.x}; }   // * (+i): inverse-FFT sign

__device__ __forceinline__ void idft4(cplx&A,cplx&B,cplx&C,cplx&D){
    cplx e0=cadd(A,C), e1=csub(A,C), o0=cadd(B,D), o1=csub(B,D);
    cplx i1 = cmuli(o1);
    A=cadd(e0,o0); B=cadd(e1,i1); C=csub(e0,o0); D=csub(e1,i1);
}
__device__ __forceinline__ void idft8(cplx a[8]){
    cplx e0=a[0],e1=a[2],e2=a[4],e3=a[6];
    cplx o0=a[1],o1=a[3],o2=a[5],o3=a[7];
    idft4(e0,e1,e2,e3); idft4(o0,o1,o2,o3);
    const float Ch = 0.70710678118654752f;
    cplx t1 = cmul(o1, cplx{ Ch, Ch});
    cplx t2 = cmuli(o2);
    cplx t3 = cmul(o3, cplx{-Ch, Ch});
    a[0]=cadd(e0,o0); a[4]=csub(e0,o0);
    a[1]=cadd(e1,t1); a[5]=csub(e1,t1);
    a[2]=cadd(e2,t2); a[6]=csub(e2,t2);
    a[3]=cadd(e3,t3); a[7]=csub(e3,t3);
}
__device__ __forceinline__ void idft16(cplx a[16]){
    cplx e[8]={a[0],a[2],a[4],a[6],a[8],a[10],a[12],a[14]};
    cplx o[8]={a[1],a[3],a[5],a[7],a[9],a[11],a[13],a[15]};
    idft8(e); idft8(o);
    const float Ch=0.70710678118654752f, c1=0.92387953251128674f, s1=0.38268343236508977f;
    const cplx w[8]={{1.f,0.f},{c1,s1},{Ch,Ch},{s1,c1},{0.f,1.f},{-s1,c1},{-Ch,Ch},{-c1,s1}};
    #pragma unroll
    for(int n=0;n<8;++n){ cplx t=cmul(o[n],w[n]); a[n]=cadd(e[n],t); a[n+8]=csub(e[n],t); }
}

#define LDSP 130   // padded row stride (cplx)
#define NR   16    // rows (or cols) per tile

// In-place FFT-128 of (blockDim.x/8) rows in fld. r=tid>>3 row, t=tid&7.
__device__ __forceinline__ void fft128_rows(cplx* fld, const cplx* tw, int tid)
{
    const int r = tid >> 3, t = tid & 7;
    cplx* row = fld + r * LDSP;
    {   cplx a[16];
        #pragma unroll
        for (int k1 = 0; k1 < 16; ++k1) a[k1] = row[t + 8*k1];
        idft16(a);
        #pragma unroll
        for (int n1 = 0; n1 < 16; ++n1) row[t + 8*n1] = cmul(a[n1], tw[(n1*t) & 127]);
    }
    __syncthreads();
    {   cplx b0[8], b1[8];
        #pragma unroll
        for (int k2 = 0; k2 < 8; ++k2) { b0[k2] = row[8*t + k2]; b1[k2] = row[8*(t+8) + k2]; }
        idft8(b0); idft8(b1);
        __syncthreads();
        #pragma unroll
        for (int n2 = 0; n2 < 8; ++n2) {
            row[ t      + 16*n2] = b0[n2];
            row[(t + 8) + 16*n2] = b1[n2];
        }
    }
    __syncthreads();
}

__device__ __forceinline__ unsigned h2_to_u(__half2 h){
    union { __half2 h; unsigned u; } v; v.h = h; return v.u;
}

// K1: row FFTs of C*G -> transposed fp16 mid[m][c*128 + i]; m==0 blocks
// also zero Wsh (replay-safe accumulation base).
__global__ __launch_bounds__(128)
void rowfft_kernel(const float* __restrict__ c_noise, __half2* __restrict__ mid,
                   float* __restrict__ Wsh)
{
    __shared__ cplx fld[NR * LDSP];
    __shared__ cplx tw[128];
    const int m   = blockIdx.x;
    const int rb  = blockIdx.y * NR;
    const int tid = threadIdx.x;

    if (m == 0) {                       // zero Wsh: 8 blocks x 2048 floats
        float4* wz = (float4*)Wsh;
        #pragma unroll
        for (int k = 0; k < 4; ++k)
            wz[blockIdx.y*512 + k*128 + tid] = {0.f, 0.f, 0.f, 0.f};
    }

    {   float s, c;
        sincosf((float)tid * (float)(2.0 * M_PI / 128.0), &s, &c);
        tw[tid] = { c, s };
    }

    const float DF = 976.5625f;                  // 1/(N*DX)
    const float Ac = 2.5132741228718345e-7f;     // 2*pi*L^2
    const float Bc = 7.8956835208714865e-7f;     // 2*pi^2*L^2
    #pragma unroll
    for (int it = 0; it < NR; ++it) {
        const int i = rb + it, j = tid;
        float fi = (float)(((i+64)&127) - 64) * DF;
        float fj = (float)(((j+64)&127) - 64) * DF;
        float G  = sqrtf(Ac * expf(-Bc * (fi*fi + fj*fj)) + 1e-12f);
        float2 cv = ((const float2*)c_noise)[(size_t)m*16384 + i*128 + j];
        fld[it*LDSP + j] = { cv.x * G, cv.y * G };
    }
    __syncthreads();

    fft128_rows(fld, tw, tid);

    // transposed fp16 store: thread = column c; 16 rows = 64 B = 4 x uint4
    const int c = tid;
    uint4* dst4 = (uint4*)(mid + (size_t)m*16384 + (size_t)c*128 + rb);
    #pragma unroll
    for (int q = 0; q < 4; ++q) {
        uint4 pk;
        cplx v0 = fld[(4*q+0)*LDSP + c];
        cplx v1 = fld[(4*q+1)*LDSP + c];
        cplx v2 = fld[(4*q+2)*LDSP + c];
        cplx v3 = fld[(4*q+3)*LDSP + c];
        pk.x = h2_to_u(__floats2half2_rn(v0.x, v0.y));
        pk.y = h2_to_u(__floats2half2_rn(v1.x, v1.y));
        pk.z = h2_to_u(__floats2half2_rn(v2.x, v2.y));
        pk.w = h2_to_u(__floats2half2_rn(v3.x, v3.y));
        dst4[q] = pk;
    }
}

// K2: structural clone of K1 -- one screen, one 16-column tile, 128 threads,
// 2 waves, 17 KiB LDS. Col FFT (rows of transposed mid); |T|^2; 16
// lane-coalesced atomicAdds per thread into shifted Wsh.
__global__ __launch_bounds__(128)
void colfft_acc_kernel(const __half2* __restrict__ mid,
                       float* __restrict__ Wsh, int M)
{
    __shared__ cplx fld[NR * LDSP];
    __shared__ cplx tw[128];
    const int m   = blockIdx.x;               // screen
    const int cb  = blockIdx.y * NR;          // column tile base (16-aligned)
    const int tid = threadIdx.x;

    {   float s, c;
        sincosf((float)tid * (float)(2.0 * M_PI / 128.0), &s, &c);
        tw[tid] = { c, s };
    }

    // load: 16-column tile of screen m (fp16 -> f32), coalesced 512B rows
    #pragma unroll
    for (int it = 0; it < NR; ++it) {
        float2 v = __half22float2(mid[(size_t)m*16384 + (size_t)(cb + it)*128 + tid]);
        fld[it*LDSP + tid] = { v.x, v.y };
    }
    __syncthreads();

    fft128_rows(fld, tw, tid);

    // |T|^2 in place (as .x): fld[it][lt] = |T2d[row lt][col cb+it]|^2
    #pragma unroll
    for (int it = 0; it < NR; ++it) {
        cplx v = fld[it*LDSP + tid];
        fld[it*LDSP + tid].x = v.x*v.x + v.y*v.y;
    }
    __syncthreads();

    // lane-coalesced accumulate into shifted W: value (it, lt2) goes to
    // Wsh[(lt2^64)*128 + (cb^64) + it]; 16 consecutive floats per
    // 16-lane group (full 64B lines), scattered over 2048 addresses.
    const int c0 = cb ^ 64;
    #pragma unroll
    for (int k = 0; k < 16; ++k) {
        int v   = k*128 + tid;                // 0..2047
        int lt2 = v >> 4, it = v & 15;
        atomicAdd(&Wsh[((lt2 ^ 64) << 7) + c0 + it], fld[it*LDSP + lt2].x);
    }
}

// K3: out[b] = (1/M) * sum_p x[b,p]^2 * Wsh[p]. Linear float4 streams;
// x[b] (64KB) + Wsh (64KB, shared) are L2-hot.
__global__ __launch_bounds__(256)
void dot_kernel(const float* __restrict__ x, const float* __restrict__ Wsh,
                float* __restrict__ out, int M)
{
    const int b = blockIdx.x;
    const float4* x4 = (const float4*)(x + (size_t)b * 16384);
    const float4* w4 = (const float4*)Wsh;
    float acc = 0.f;
    #pragma unroll 4
    for (int k = threadIdx.x; k < 4096; k += 256) {
        float4 xv = x4[k], wv = w4[k];
        acc = fmaf(xv.x*xv.x, wv.x, acc);
        acc = fmaf(xv.y*xv.y, wv.y, acc);
        acc = fmaf(xv.z*xv.z, wv.z, acc);
        acc = fmaf(xv.w*xv.w, wv.w, acc);
    }
    #pragma unroll
    for (int off = 32; off > 0; off >>= 1) acc += __shfl_down(acc, off);
    __shared__ float part[4];
    if ((threadIdx.x & 63) == 0) part[threadIdx.x >> 6] = acc;
    __syncthreads();
    if (threadIdx.x == 0)
        out[b] = (part[0] + part[1] + part[2] + part[3]) / (float)M;
}

extern "C" void kernel_launch(void* const* d_in, const int* in_sizes, int n_in,
                              void* d_out, int out_size, void* d_ws, size_t ws_size,
                              hipStream_t stream)
{
    (void)n_in; (void)ws_size;
    const float* x_in    = (const float*)d_in[0];
    // d_in[1] (phases) provably does not affect the output (|exp(i*phase)|=1).
    const float* c_noise = (const float*)d_in[2];

    const int M = in_sizes[2] / (128*128*2);   // 100
    const int B = out_size;                    // 32

    __half2* mid = (__half2*)d_ws;                                   // 6.55 MB
    float*   Wsh = (float*)((char*)d_ws + (size_t)M*16384*sizeof(__half2)); // 64 KB

    rowfft_kernel    <<<dim3(M, 8), dim3(128), 0, stream>>>(c_noise, mid, Wsh);
    colfft_acc_kernel<<<dim3(M, 8), dim3(128), 0, stream>>>(mid, Wsh, M);
    dot_kernel       <<<dim3(B),    dim3(256), 0, stream>>>(x_in, Wsh,
                                                            (float*)d_out, M);
}